// Round 12
// baseline (408.865 us; speedup 1.0000x reference)
//
#include <hip/hip_runtime.h>

// build-id: r12-r9gemm-attn-direct

#define E_DIM 1024
#define H_DIM 16
#define D_DIM 64
#define S_SEQ 1024
#define B_BATCH 4

typedef __bf16 bf16;
typedef __attribute__((ext_vector_type(8))) __bf16 bf16x8;
typedef __attribute__((ext_vector_type(4))) __bf16 bf16x4;
typedef __attribute__((ext_vector_type(4))) float f32x4;

// ---------------------------------------------------------------- async copy
__device__ __forceinline__ void cp_async16(const bf16* g, bf16* l) {
  __builtin_amdgcn_global_load_lds(
      (const __attribute__((address_space(1))) void*)g,
      (__attribute__((address_space(3))) void*)l, 16, 0, 0);
}

// ---------------------------------------------------------------- GEMM (B^T)
// C[M,N] = A[:,z*Kper..+Kper] * BT[:,z*Kper..+Kper]^T (+ bias)
// modes: 1 = bf16 row-major (z-offset partials), 2 = gelu->bf16, 3 = qkv-split
// r9 kernel verbatim (measured best: fc 49us, MfmaUtil 26%, 92 VGPR).
// BM=BN=256, BK=64, 512 thr = 8 waves (2Mx4N), per-wave 128x64, acc[8][4].
// Schedule-structure experiments r1-r11 (drain-0 / coarse ring / phase-split
// / minimal / 8-phase) all pin at 22-26% MfmaUtil -> schedule is not the
// lever at this size; minimal sync is fastest. Per K-tile:
//   gate vmcnt(0); s_barrier; stage(t+1) -> freed slot; 24 ds_read; 64 MFMA.
// Staging: 8 rows x 128 B sweeps; granule g of row r at slot g^(r&7) via
// pre-swizzled global source (gload_lds linear-dest constraint).
#define BM 256
#define BN 256
#define BK 64
#define BOFF 32768           // elements: B slots start after 2 A slots
#define CS_STRIDE 264        // epilogue C-stage row stride (256 + 8)

__global__ __launch_bounds__(512, 2) void gemm256(
    const bf16* __restrict__ A, const bf16* __restrict__ BT,
    const float* __restrict__ bias, void* __restrict__ Cout,
    int M, int N, int Ktot, int Kper, int mode)
{
  __shared__ bf16 smem[67584];          // 135168 B: ring 65536 el, C-stage 67584
  const int tid  = threadIdx.x;
  const int wave = tid >> 6;
  const int lane = tid & 63;
  const int quad = lane >> 4;
  const int ln16 = lane & 15;
  const int wr = wave >> 2;             // 0..1  (row half of 256)
  const int wc = wave & 3;              // 0..3  (col quarter of 256)
  const int z  = blockIdx.z;

  // bijective XCD-chunk swizzle (all grids have nwg % 8 == 0)
  const int nwg = gridDim.x * gridDim.y;
  int id = blockIdx.y * gridDim.x + blockIdx.x;
  id = (id & 7) * (nwg >> 3) + (id >> 3);
  const int bn = (id % gridDim.x) * BN;
  const int bm = (id / gridDim.x) * BM;

  // staging: per sweep, wave covers 8 rows x 8 granules (128 B rows);
  // lane = lr*8+lg; 4 sweeps x 64 rows cover 256 rows per operand.
  const int lr = lane >> 3;             // row offset within 8-row stripe
  const int lg = lane & 7;              // dest granule slot
  const int gsrc = (lg ^ lr) * 8;       // swizzled source granule (elements)
  const bf16* Ag = A  + (size_t)(bm + wave * 8 + lr) * Ktot + (size_t)z * Kper + gsrc;
  const bf16* Bg = BT + (size_t)(bn + wave * 8 + lr) * Ktot + (size_t)z * Kper + gsrc;

  f32x4 acc[8][4];
#pragma unroll
  for (int i = 0; i < 8; ++i)
#pragma unroll
    for (int j = 0; j < 4; ++j) acc[i][j] = (f32x4){0.f, 0.f, 0.f, 0.f};

  // stage K-tile tt into dbuf slot ss: A 4 sweeps + B 4 sweeps (8 vmem/thread)
  auto stage = [&](int tt, int ss) {
    const size_t ko = (size_t)tt * BK;
    bf16* AsW = smem + ss * 16384 + wave * 512;          // wave-uniform
    bf16* BsW = smem + BOFF + ss * 16384 + wave * 512;
#pragma unroll
    for (int i = 0; i < 4; ++i) {
      cp_async16(Ag + ko + (size_t)(i * 64) * Ktot, AsW + i * 4096);
      cp_async16(Bg + ko + (size_t)(i * 64) * Ktot, BsW + i * 4096);
    }
  };

  const int nt = Kper >> 6;             // BK=64; >= 8 for all call sites
  stage(0, 0);

  for (int t = 0; t < nt; ++t) {
    // gate: only outstanding vmem = stage(t), issued one iteration ago
    asm volatile("s_waitcnt vmcnt(0)" ::: "memory");
    __builtin_amdgcn_s_barrier();       // publish tile t; slot (t+1)&1 free

    if (t + 1 < nt) stage(t + 1, (t + 1) & 1);

    const bf16* At = smem + (t & 1) * 16384;
    const bf16* Bt = smem + BOFF + (t & 1) * 16384;
#pragma unroll
    for (int ks = 0; ks < 2; ++ks) {
      const int g8 = ((ks * 4 + quad) ^ (ln16 & 7)) * 8;
      bf16x8 afr[8], bfr[4];
#pragma unroll
      for (int j = 0; j < 4; ++j)
        bfr[j] = *(const bf16x8*)&Bt[(wc * 64 + j * 16 + ln16) * 64 + g8];
#pragma unroll
      for (int i = 0; i < 8; ++i)
        afr[i] = *(const bf16x8*)&At[(wr * 128 + i * 16 + ln16) * 64 + g8];
#pragma unroll
      for (int i = 0; i < 8; ++i)
#pragma unroll
        for (int j = 0; j < 4; ++j)
          acc[i][j] = __builtin_amdgcn_mfma_f32_16x16x32_bf16(
              afr[i], bfr[j], acc[i][j], 0, 0, 0);
    }
  }

  // ---- epilogue: single-pass LDS stage, coalesced 16B stores
  __syncthreads();
  const int which = bn >> 10;           // mode 3: 0=q 1=k 2=v
  const int h0    = (bn & 1023) >> 6;   // first of 4 heads in this tile
  bf16* Cb = (bf16*)Cout;

#pragma unroll
  for (int j = 0; j < 4; ++j) {
    const int col = wc * 64 + j * 16 + ln16;
    const float bv = bias ? bias[bn + col] : 0.f;
#pragma unroll
    for (int i = 0; i < 8; ++i) {
      const int row0 = wr * 128 + i * 16 + quad * 4;
#pragma unroll
      for (int r = 0; r < 4; ++r) {
        float v = acc[i][j][r] + bv;
        if (mode == 2)
          v = v / (1.f + __expf(-1.5957691216057308f * (v + 0.044715f * v * v * v)));
        else if (mode == 3 && which == 0)
          v *= 0.18033688011112042f;    // 0.125 / ln2 (attn uses exp2)
        smem[(row0 + r) * CS_STRIDE + col] = (bf16)v;
      }
    }
  }
  __syncthreads();
  if (mode == 3) {
#pragma unroll
    for (int pass = 0; pass < 16; ++pass) {
      const int f = pass * 512 + tid;          // 8192 granules (256 x 32)
      const int row = f >> 5, cg = f & 31;
      const bf16x8 val = *(const bf16x8*)&smem[row * CS_STRIDE + cg * 8];
      const int sb = bm + row;
      const int s = sb >> 2, b = sb & 3;
      const int h = h0 + (cg >> 3), d8 = cg & 7;
      bf16* dst = Cb + (size_t)which * 4194304
                + ((size_t)(b * 16 + h) * 1024 + s) * 64 + d8 * 8;
      *(bf16x8*)dst = val;
    }
  } else {
    bf16* Cz = Cb + (size_t)z * M * N;
#pragma unroll
    for (int pass = 0; pass < 16; ++pass) {
      const int f = pass * 512 + tid;
      const int row = f >> 5, cg = f & 31;
      const bf16x8 val = *(const bf16x8*)&smem[row * CS_STRIDE + cg * 8];
      *(bf16x8*)(Cz + (size_t)(bm + row) * N + bn + cg * 8) = val;
    }
  }
}

// ------ fused: reduce proj bf16 partials + bias + residual -> xmid, + LN2 -> hbuf
// pp rows are (b*S+s); x/xmid rows are (s*B+b)
__global__ __launch_bounds__(256) void reduce_proj_ln(
    const float* __restrict__ x, const float* __restrict__ bias,
    const bf16* __restrict__ pp, const float* __restrict__ gam,
    const float* __restrict__ bet, float* __restrict__ xmid,
    bf16* __restrict__ hbuf)
{
  const int t = blockIdx.x;               // row in (s*B+b) order
  const int tid = threadIdx.x;
  const int s = t >> 2, b = t & 3;
  const size_t prow = ((size_t)(b * S_SEQ + s)) * E_DIM + tid * 4;
  const float4 xv = ((const float4*)(x + (size_t)t * E_DIM))[tid];
  const float4 bv = ((const float4*)bias)[tid];
  const bf16x4 p0 = *(const bf16x4*)&pp[prow];
  const bf16x4 p1 = *(const bf16x4*)&pp[prow + (size_t)S_SEQ * B_BATCH * E_DIM];
  float4 v;
  v.x = xv.x + bv.x + (float)p0[0] + (float)p1[0];
  v.y = xv.y + bv.y + (float)p0[1] + (float)p1[1];
  v.z = xv.z + bv.z + (float)p0[2] + (float)p1[2];
  v.w = xv.w + bv.w + (float)p0[3] + (float)p1[3];
  ((float4*)(xmid + (size_t)t * E_DIM))[tid] = v;

  float sm  = v.x + v.y + v.z + v.w;
  float ss = v.x*v.x + v.y*v.y + v.z*v.z + v.w*v.w;
#pragma unroll
  for (int off = 1; off < 64; off <<= 1) {
    sm += __shfl_xor(sm, off);
    ss += __shfl_xor(ss, off);
  }
  __shared__ float rs[4], rss[4];
  const int wave = tid >> 6;
  if ((tid & 63) == 0) { rs[wave] = sm; rss[wave] = ss; }
  __syncthreads();
  sm = rs[0] + rs[1] + rs[2] + rs[3];
  ss = rss[0] + rss[1] + rss[2] + rss[3];
  const float mu   = sm * (1.f / E_DIM);
  const float rstd = rsqrtf(ss * (1.f / E_DIM) - mu * mu + 1e-5f);
  const float4 g4 = ((const float4*)gam)[tid];
  const float4 b4 = ((const float4*)bet)[tid];
  bf16* o = hbuf + (size_t)t * E_DIM + tid * 4;
  o[0] = (bf16)((v.x - mu) * rstd * g4.x + b4.x);
  o[1] = (bf16)((v.y - mu) * rstd * g4.y + b4.y);
  o[2] = (bf16)((v.z - mu) * rstd * g4.z + b4.z);
  o[3] = (bf16)((v.w - mu) * rstd * g4.w + b4.w);
}

// --------------- reduce out bf16 partials (x4) + bias + residual -> out
__global__ __launch_bounds__(256) void reduce_out(
    const float* __restrict__ xmid, const float* __restrict__ bias,
    const bf16* __restrict__ op, float* __restrict__ out)
{
  const int i4 = blockIdx.x * 256 + threadIdx.x;  // 4-el granule, < 2^20
  const int e4 = i4 & 255;
  const size_t base = (size_t)i4 * 4;
  const size_t stride = (size_t)S_SEQ * B_BATCH * E_DIM;
  const float4 a = ((const float4*)xmid)[i4];
  const float4 bv = ((const float4*)bias)[e4];
  const bf16x4 p0 = *(const bf16x4*)&op[base];
  const bf16x4 p1 = *(const bf16x4*)&op[base + stride];
  const bf16x4 p2 = *(const bf16x4*)&op[base + 2 * stride];
  const bf16x4 p3 = *(const bf16x4*)&op[base + 3 * stride];
  float4 o;
  o.x = a.x + bv.x + (float)p0[0] + (float)p1[0] + (float)p2[0] + (float)p3[0];
  o.y = a.y + bv.y + (float)p0[1] + (float)p1[1] + (float)p2[1] + (float)p3[1];
  o.z = a.z + bv.z + (float)p0[2] + (float)p1[2] + (float)p2[2] + (float)p3[2];
  o.w = a.w + bv.w + (float)p0[3] + (float)p1[3] + (float)p2[3] + (float)p3[3];
  ((float4*)out)[i4] = o;
}

// ------------------------------------- fused transpose f32->bf16 (all weights)
__global__ __launch_bounds__(256) void transpose_all(
    const float* __restrict__ w_attn, bf16* __restrict__ wT_attn,
    const float* __restrict__ w_proj, bf16* __restrict__ wT_proj,
    const float* __restrict__ w_fc,   bf16* __restrict__ wT_fc,
    const float* __restrict__ w_out,  bf16* __restrict__ wT_out)
{
  int bid = blockIdx.x;
  const float* in; bf16* outp; int R, C, bx;
  if (bid < 3072)      { in = w_attn; outp = wT_attn; R = 1024; C = 3072; bx = 96; }
  else if (bid < 4096) { in = w_proj; outp = wT_proj; R = 1024; C = 1024; bx = 32; bid -= 3072; }
  else if (bid < 8192) { in = w_fc;   outp = wT_fc;   R = 1024; C = 4096; bx = 128; bid -= 4096; }
  else                 { in = w_out;  outp = wT_out;  R = 4096; C = 1024; bx = 32; bid -= 8192; }
  __shared__ float tile[32][33];
  const int tx = threadIdx.x & 31;
  const int ty = threadIdx.x >> 5;
  const int c0 = (bid % bx) * 32;
  const int r0 = (bid / bx) * 32;
#pragma unroll
  for (int k = 0; k < 4; ++k)
    tile[ty + k*8][tx] = in[(size_t)(r0 + ty + k*8) * C + c0 + tx];
  __syncthreads();
#pragma unroll
  for (int k = 0; k < 4; ++k)
    outp[(size_t)(c0 + ty + k*8) * R + r0 + tx] = (bf16)tile[tx][ty + k*8];
}

// ------------------------------------------------------------------ layernorm
__global__ __launch_bounds__(256) void layernorm_bf16(
    const float* __restrict__ x, const float* __restrict__ gam,
    const float* __restrict__ bet, bf16* __restrict__ out)
{
  const int t = blockIdx.x;
  const int tid = threadIdx.x;
  const float4 v = ((const float4*)(x + (size_t)t * E_DIM))[tid];
  float s  = v.x + v.y + v.z + v.w;
  float ss = v.x*v.x + v.y*v.y + v.z*v.z + v.w*v.w;
#pragma unroll
  for (int off = 1; off < 64; off <<= 1) {
    s  += __shfl_xor(s, off);
    ss += __shfl_xor(ss, off);
  }
  __shared__ float rs[4], rss[4];
  const int wave = tid >> 6;
  if ((tid & 63) == 0) { rs[wave] = s; rss[wave] = ss; }
  __syncthreads();
  s  = rs[0] + rs[1] + rs[2] + rs[3];
  ss = rss[0] + rss[1] + rss[2] + rss[3];
  const float mu   = s * (1.f / E_DIM);
  const float rstd = rsqrtf(ss * (1.f / E_DIM) - mu * mu + 1e-5f);
  const float4 g4 = ((const float4*)gam)[tid];
  const float4 b4 = ((const float4*)bet)[tid];
  bf16* o = out + (size_t)t * E_DIM + tid * 4;
  o[0] = (bf16)((v.x - mu) * rstd * g4.x + b4.x);
  o[1] = (bf16)((v.y - mu) * rstd * g4.y + b4.y);
  o[2] = (bf16)((v.z - mu) * rstd * g4.z + b4.z);
  o[3] = (bf16)((v.w - mu) * rstd * g4.w + b4.w);
}

// ------------------------------- V transpose: vk [head][S][64] -> vt [head][64][S]
__global__ __launch_bounds__(256) void transpose_v(
    const bf16* __restrict__ vk, bf16* __restrict__ vt)
{
  __shared__ bf16 tile[64 * 66];
  const int head = blockIdx.y;
  const int s0 = blockIdx.x * 64;
  const int tid = threadIdx.x;
  for (int f = tid; f < 512; f += 256) {
    const int s = f >> 3, g = f & 7;
    const bf16x8 val = *(const bf16x8*)&vk[((size_t)head * S_SEQ + s0 + s) * 64 + g * 8];
#pragma unroll
    for (int i = 0; i < 8; ++i) tile[s * 66 + g * 8 + i] = val[i];
  }
  __syncthreads();
  for (int f = tid; f < 512; f += 256) {
    const int d = f >> 3, g = f & 7;
    bf16x8 o;
#pragma unroll
    for (int i = 0; i < 8; ++i) o[i] = tile[(g * 8 + i) * 66 + d];
    *(bf16x8*)&vt[((size_t)head * 64 + d) * S_SEQ + s0 + g * 8] = o;
  }
}

// ---------------------------------------------------- flash attention (MFMA)
// Q,K: [head][S][64] bf16 (Q pre-scaled by 1/(8 ln2) -> use exp2);
// Vt: [head][64][S] bf16; Out: [B][S][E] bf16 (merged heads).
// DIRECT-GLOBAL K/V (guide m169: at S=1024 K/V are L2-resident; LDS staging
// was pure overhead): K-frags are 16 contiguous B along d; Vt-frags 16
// contiguous B along s -> per-lane global_load_dwordx4, L1/L2-served.
// ZERO barriers in the KV loop; waves fully independent; LDS = Ps only
// (8.7 KB -> 4+ blocks/CU, 16 waves/CU latency hiding).
// 64 q-rows per block (16 per wave). NO max-stabilization: scores bounded
// (|s|<~4), softmax = exp2(s')/sum exp2(s'); l reduced once at the end.
// AT_PAD=68: Ps scalar writes conflict-free; Ps rows are wave-private.
#define AT_PAD 68
__global__ __launch_bounds__(256) void attn_mfma(
    const bf16* __restrict__ Q, const bf16* __restrict__ K,
    const bf16* __restrict__ Vt, bf16* __restrict__ Out)
{
  __shared__ bf16 Ps[64 * AT_PAD];
  const int head = blockIdx.x;
  const int q0 = blockIdx.y * 64;
  const int tid = threadIdx.x;
  const int wave = tid >> 6, lane = tid & 63;
  const int quad = lane >> 4, ln16 = lane & 15;

  // Q A-fragments direct from global (row = q-index, 8 contiguous k-elements)
  const bf16* qg = Q + ((size_t)head * S_SEQ + q0) * 64;
  bf16x8 qfr[2];
#pragma unroll
  for (int ks = 0; ks < 2; ++ks)
    qfr[ks] = *(const bf16x8*)&qg[(size_t)(wave * 16 + ln16) * 64 + ks * 32 + quad * 8];

  f32x4 Oa[4];
  float l_i[4];
#pragma unroll
  for (int j = 0; j < 4; ++j) Oa[j] = (f32x4){0.f, 0.f, 0.f, 0.f};
#pragma unroll
  for (int r = 0; r < 4; ++r) l_i[r] = 0.f;

  const bf16* kg = K + (size_t)head * S_SEQ * 64;
  const bf16* vg = Vt + (size_t)head * 64 * S_SEQ;
  const int qrow = wave * 16;

  for (int kt = 0; kt < S_SEQ; kt += 64) {
    // ---- S = Q K^T  (K-frags direct: rows kt+jn*16+ln16, 16B at d-offset)
    f32x4 sacc[4];
#pragma unroll
    for (int jn = 0; jn < 4; ++jn) sacc[jn] = (f32x4){0.f, 0.f, 0.f, 0.f};
#pragma unroll
    for (int ks = 0; ks < 2; ++ks) {
#pragma unroll
      for (int jn = 0; jn < 4; ++jn) {
        const bf16x8 kf = *(const bf16x8*)
            &kg[(size_t)(kt + jn * 16 + ln16) * 64 + ks * 32 + quad * 8];
        sacc[jn] = __builtin_amdgcn_mfma_f32_16x16x32_bf16(qfr[ks], kf, sacc[jn], 0, 0, 0);
      }
    }
    // ---- unnormalized softmax: p = 2^s (C-layout row = quad*4+r)
#pragma unroll
    for (int r = 0; r < 4; ++r) {
      const float p0 = exp2f(sacc[0][r]);
      const float p1 = exp2f(sacc[1][r]);
      const float p2 = exp2f(sacc[2][r]);
      const float p3 = exp2f(sacc[3][r]);
      l_i[r] += (p0 + p1) + (p2 + p3);
      const int prow = qrow + quad * 4 + r;
      Ps[prow * AT_PAD +  0 + ln16] = (bf16)p0;
      Ps[prow * AT_PAD + 16 + ln16] = (bf16)p1;
      Ps[prow * AT_PAD + 32 + ln16] = (bf16)p2;
      Ps[prow * AT_PAD + 48 + ln16] = (bf16)p3;
    }
    // P round-trip is wave-local (rows qrow..qrow+15): LDS drain, no barrier
    asm volatile("s_waitcnt lgkmcnt(0)" ::: "memory");
    // ---- O += P V  (V-frags direct: Vt row = d, 16B at s-offset kt+..)
#pragma unroll
    for (int ks = 0; ks < 2; ++ks) {
      const bf16x8 pf = *(const bf16x8*)&Ps[(qrow + ln16) * AT_PAD + ks*32 + quad*8];
#pragma unroll
      for (int jn = 0; jn < 4; ++jn) {
        const bf16x8 vf = *(const bf16x8*)
            &vg[(size_t)(jn * 16 + ln16) * S_SEQ + kt + ks * 32 + quad * 8];
        Oa[jn] = __builtin_amdgcn_mfma_f32_16x16x32_bf16(pf, vf, Oa[jn], 0, 0, 0);
      }
    }
  }

  // final l reduction across the 16 lanes of each row group (deferred, once)
#pragma unroll
  for (int r = 0; r < 4; ++r) {
    float l = l_i[r];
#pragma unroll
    for (int off = 1; off < 16; off <<= 1) l += __shfl_xor(l, off);
    l_i[r] = 1.f / l;
  }

  const int b = head >> 4, h = head & 15;
#pragma unroll
  for (int jn = 0; jn < 4; ++jn)
#pragma unroll
    for (int r = 0; r < 4; ++r) {
      const int srow = q0 + qrow + quad * 4 + r;
      Out[((size_t)(b * S_SEQ) + srow) * E_DIM + h * 64 + jn * 16 + ln16] =
          (bf16)(Oa[jn][r] * l_i[r]);
    }
}

// -------------------------------------------------------------------- launch
extern "C" void kernel_launch(void* const* d_in, const int* in_sizes, int n_in,
                              void* d_out, int out_size, void* d_ws, size_t ws_size,
                              hipStream_t stream)
{
  const float* x      = (const float*)d_in[0];
  const float* ln1_g  = (const float*)d_in[1];
  const float* ln1_b  = (const float*)d_in[2];
  const float* w_attn = (const float*)d_in[3];
  const float* b_attn = (const float*)d_in[4];
  const float* w_proj = (const float*)d_in[5];
  const float* b_proj = (const float*)d_in[6];
  const float* ln2_g  = (const float*)d_in[7];
  const float* ln2_b  = (const float*)d_in[8];
  const float* w_fc   = (const float*)d_in[9];
  const float* b_fc   = (const float*)d_in[10];
  const float* w_out  = (const float*)d_in[11];
  const float* b_out  = (const float*)d_in[12];
  float* out = (float*)d_out;

  char* p = (char*)d_ws;
  bf16* wT_attn = (bf16*)p; p += (size_t)3072 * 1024 * 2;   //  6 MB
  bf16* wT_proj = (bf16*)p; p += (size_t)1024 * 1024 * 2;   //  2 MB
  bf16* wT_fc   = (bf16*)p; p += (size_t)4096 * 1024 * 2;   //  8 MB
  bf16* wT_out  = (bf16*)p; p += (size_t)1024 * 4096 * 2;   //  8 MB
  bf16* hbuf    = (bf16*)p; p += (size_t)4096 * 1024 * 2;   //  8 MB (also amerged)
  bf16* amerged = hbuf;       // lifetime [attn, proj_sk] inside hbuf's idle window
  bf16* mfc     = (bf16*)p; p += (size_t)4096 * 4096 * 2;   // 32 MB
  char* part    = p;        p += (size_t)64 * 1024 * 1024;  // 64 MB union
  bf16*  qsplit   = (bf16*)part;                               // q,k,vk: 24 MB
  bf16*  vtb      = (bf16*)(part + (size_t)24 * 1024 * 1024); //  8 MB
  bf16*  projpart = (bf16*)(part + (size_t)32 * 1024 * 1024); // 16 MB (bf16 x2)
  bf16*  outpart  = (bf16*)part;                               // 32 MB (bf16 x4, later)
  float* xmid   = (float*)p; p += (size_t)4194304 * 4;      // 16 MB

  transpose_all<<<12288, 256, 0, stream>>>(w_attn, wT_attn, w_proj, wT_proj,
                                           w_fc, wT_fc, w_out, wT_out);

  layernorm_bf16<<<4096, 256, 0, stream>>>(x, ln1_g, ln1_b, hbuf);
  // qkv GEMM with fused head-split epilogue (mode 3) -> qsplit {q,k,vk}
  gemm256<<<dim3(12, 16), 512, 0, stream>>>(hbuf, wT_attn, b_attn, qsplit,
                                            4096, 3072, 1024, 1024, 3);
  transpose_v<<<dim3(16, 64), 256, 0, stream>>>(qsplit + (size_t)2 * 4194304, vtb);
  attn_mfma<<<dim3(64, 16), 256, 0, stream>>>(qsplit, qsplit + 4194304, vtb, amerged);
  // proj: split-K x2 bf16 partials, fused reduce(+bias+residual)+LN2
  gemm256<<<dim3(4, 16, 2), 512, 0, stream>>>(amerged, wT_proj, nullptr, projpart,
                                              4096, 1024, 1024, 512, 1);
  reduce_proj_ln<<<4096, 256, 0, stream>>>(x, b_proj, projpart, ln2_g, ln2_b,
                                           xmid, hbuf);
  gemm256<<<dim3(16, 16), 512, 0, stream>>>(hbuf, wT_fc, b_fc, mfc,
                                            4096, 4096, 1024, 1024, 2);
  // out: split-K x4 bf16 partials, fused reduce(+bias+residual) -> out
  gemm256<<<dim3(4, 16, 4), 512, 0, stream>>>(mfc, wT_out, nullptr, outpart,
                                              4096, 1024, 4096, 1024, 1);
  reduce_out<<<4096, 256, 0, stream>>>(xmid, b_out, outpart, out);
}

// Round 13
// 338.993 us; speedup vs baseline: 1.2061x; 1.2061x over previous
//
#include <hip/hip_runtime.h>

// build-id: r13-r9gemm-attn-gloadlds-dbuf

#define E_DIM 1024
#define H_DIM 16
#define D_DIM 64
#define S_SEQ 1024
#define B_BATCH 4

typedef __bf16 bf16;
typedef __attribute__((ext_vector_type(8))) __bf16 bf16x8;
typedef __attribute__((ext_vector_type(4))) __bf16 bf16x4;
typedef __attribute__((ext_vector_type(4))) float f32x4;

// ---------------------------------------------------------------- async copy
__device__ __forceinline__ void cp_async16(const bf16* g, bf16* l) {
  __builtin_amdgcn_global_load_lds(
      (const __attribute__((address_space(1))) void*)g,
      (__attribute__((address_space(3))) void*)l, 16, 0, 0);
}

// ---------------------------------------------------------------- GEMM (B^T)
// C[M,N] = A[:,z*Kper..+Kper] * BT[:,z*Kper..+Kper]^T (+ bias)
// modes: 1 = bf16 row-major (z-offset partials), 2 = gelu->bf16, 3 = qkv-split
// r9 kernel verbatim (measured best: fc 49us, MfmaUtil 26%, 92 VGPR).
// BM=BN=256, BK=64, 512 thr = 8 waves (2Mx4N), per-wave 128x64, acc[8][4].
// Schedule-structure experiments r1-r11 (drain-0 / coarse ring / phase-split
// / minimal / 8-phase) all pin at 22-26% MfmaUtil -> schedule is not the
// lever at this size; minimal sync is fastest. Per K-tile:
//   gate vmcnt(0); s_barrier; stage(t+1) -> freed slot; 24 ds_read; 64 MFMA.
// Staging: 8 rows x 128 B sweeps; granule g of row r at slot g^(r&7) via
// pre-swizzled global source (gload_lds linear-dest constraint).
#define BM 256
#define BN 256
#define BK 64
#define BOFF 32768           // elements: B slots start after 2 A slots
#define CS_STRIDE 264        // epilogue C-stage row stride (256 + 8)

__global__ __launch_bounds__(512, 2) void gemm256(
    const bf16* __restrict__ A, const bf16* __restrict__ BT,
    const float* __restrict__ bias, void* __restrict__ Cout,
    int M, int N, int Ktot, int Kper, int mode)
{
  __shared__ bf16 smem[67584];          // 135168 B: ring 65536 el, C-stage 67584
  const int tid  = threadIdx.x;
  const int wave = tid >> 6;
  const int lane = tid & 63;
  const int quad = lane >> 4;
  const int ln16 = lane & 15;
  const int wr = wave >> 2;             // 0..1  (row half of 256)
  const int wc = wave & 3;              // 0..3  (col quarter of 256)
  const int z  = blockIdx.z;

  // bijective XCD-chunk swizzle (all grids have nwg % 8 == 0)
  const int nwg = gridDim.x * gridDim.y;
  int id = blockIdx.y * gridDim.x + blockIdx.x;
  id = (id & 7) * (nwg >> 3) + (id >> 3);
  const int bn = (id % gridDim.x) * BN;
  const int bm = (id / gridDim.x) * BM;

  // staging: per sweep, wave covers 8 rows x 8 granules (128 B rows);
  // lane = lr*8+lg; 4 sweeps x 64 rows cover 256 rows per operand.
  const int lr = lane >> 3;             // row offset within 8-row stripe
  const int lg = lane & 7;              // dest granule slot
  const int gsrc = (lg ^ lr) * 8;       // swizzled source granule (elements)
  const bf16* Ag = A  + (size_t)(bm + wave * 8 + lr) * Ktot + (size_t)z * Kper + gsrc;
  const bf16* Bg = BT + (size_t)(bn + wave * 8 + lr) * Ktot + (size_t)z * Kper + gsrc;

  f32x4 acc[8][4];
#pragma unroll
  for (int i = 0; i < 8; ++i)
#pragma unroll
    for (int j = 0; j < 4; ++j) acc[i][j] = (f32x4){0.f, 0.f, 0.f, 0.f};

  // stage K-tile tt into dbuf slot ss: A 4 sweeps + B 4 sweeps (8 vmem/thread)
  auto stage = [&](int tt, int ss) {
    const size_t ko = (size_t)tt * BK;
    bf16* AsW = smem + ss * 16384 + wave * 512;          // wave-uniform
    bf16* BsW = smem + BOFF + ss * 16384 + wave * 512;
#pragma unroll
    for (int i = 0; i < 4; ++i) {
      cp_async16(Ag + ko + (size_t)(i * 64) * Ktot, AsW + i * 4096);
      cp_async16(Bg + ko + (size_t)(i * 64) * Ktot, BsW + i * 4096);
    }
  };

  const int nt = Kper >> 6;             // BK=64; >= 8 for all call sites
  stage(0, 0);

  for (int t = 0; t < nt; ++t) {
    // gate: only outstanding vmem = stage(t), issued one iteration ago
    asm volatile("s_waitcnt vmcnt(0)" ::: "memory");
    __builtin_amdgcn_s_barrier();       // publish tile t; slot (t+1)&1 free

    if (t + 1 < nt) stage(t + 1, (t + 1) & 1);

    const bf16* At = smem + (t & 1) * 16384;
    const bf16* Bt = smem + BOFF + (t & 1) * 16384;
#pragma unroll
    for (int ks = 0; ks < 2; ++ks) {
      const int g8 = ((ks * 4 + quad) ^ (ln16 & 7)) * 8;
      bf16x8 afr[8], bfr[4];
#pragma unroll
      for (int j = 0; j < 4; ++j)
        bfr[j] = *(const bf16x8*)&Bt[(wc * 64 + j * 16 + ln16) * 64 + g8];
#pragma unroll
      for (int i = 0; i < 8; ++i)
        afr[i] = *(const bf16x8*)&At[(wr * 128 + i * 16 + ln16) * 64 + g8];
#pragma unroll
      for (int i = 0; i < 8; ++i)
#pragma unroll
        for (int j = 0; j < 4; ++j)
          acc[i][j] = __builtin_amdgcn_mfma_f32_16x16x32_bf16(
              afr[i], bfr[j], acc[i][j], 0, 0, 0);
    }
  }

  // ---- epilogue: single-pass LDS stage, coalesced 16B stores
  __syncthreads();
  const int which = bn >> 10;           // mode 3: 0=q 1=k 2=v
  const int h0    = (bn & 1023) >> 6;   // first of 4 heads in this tile
  bf16* Cb = (bf16*)Cout;

#pragma unroll
  for (int j = 0; j < 4; ++j) {
    const int col = wc * 64 + j * 16 + ln16;
    const float bv = bias ? bias[bn + col] : 0.f;
#pragma unroll
    for (int i = 0; i < 8; ++i) {
      const int row0 = wr * 128 + i * 16 + quad * 4;
#pragma unroll
      for (int r = 0; r < 4; ++r) {
        float v = acc[i][j][r] + bv;
        if (mode == 2)
          v = v / (1.f + __expf(-1.5957691216057308f * (v + 0.044715f * v * v * v)));
        else if (mode == 3 && which == 0)
          v *= 0.18033688011112042f;    // 0.125 / ln2 (attn uses exp2)
        smem[(row0 + r) * CS_STRIDE + col] = (bf16)v;
      }
    }
  }
  __syncthreads();
  if (mode == 3) {
#pragma unroll
    for (int pass = 0; pass < 16; ++pass) {
      const int f = pass * 512 + tid;          // 8192 granules (256 x 32)
      const int row = f >> 5, cg = f & 31;
      const bf16x8 val = *(const bf16x8*)&smem[row * CS_STRIDE + cg * 8];
      const int sb = bm + row;
      const int s = sb >> 2, b = sb & 3;
      const int h = h0 + (cg >> 3), d8 = cg & 7;
      bf16* dst = Cb + (size_t)which * 4194304
                + ((size_t)(b * 16 + h) * 1024 + s) * 64 + d8 * 8;
      *(bf16x8*)dst = val;
    }
  } else {
    bf16* Cz = Cb + (size_t)z * M * N;
#pragma unroll
    for (int pass = 0; pass < 16; ++pass) {
      const int f = pass * 512 + tid;
      const int row = f >> 5, cg = f & 31;
      const bf16x8 val = *(const bf16x8*)&smem[row * CS_STRIDE + cg * 8];
      *(bf16x8*)(Cz + (size_t)(bm + row) * N + bn + cg * 8) = val;
    }
  }
}

// ------ fused: reduce proj bf16 partials + bias + residual -> xmid, + LN2 -> hbuf
// pp rows are (b*S+s); x/xmid rows are (s*B+b)
__global__ __launch_bounds__(256) void reduce_proj_ln(
    const float* __restrict__ x, const float* __restrict__ bias,
    const bf16* __restrict__ pp, const float* __restrict__ gam,
    const float* __restrict__ bet, float* __restrict__ xmid,
    bf16* __restrict__ hbuf)
{
  const int t = blockIdx.x;               // row in (s*B+b) order
  const int tid = threadIdx.x;
  const int s = t >> 2, b = t & 3;
  const size_t prow = ((size_t)(b * S_SEQ + s)) * E_DIM + tid * 4;
  const float4 xv = ((const float4*)(x + (size_t)t * E_DIM))[tid];
  const float4 bv = ((const float4*)bias)[tid];
  const bf16x4 p0 = *(const bf16x4*)&pp[prow];
  const bf16x4 p1 = *(const bf16x4*)&pp[prow + (size_t)S_SEQ * B_BATCH * E_DIM];
  float4 v;
  v.x = xv.x + bv.x + (float)p0[0] + (float)p1[0];
  v.y = xv.y + bv.y + (float)p0[1] + (float)p1[1];
  v.z = xv.z + bv.z + (float)p0[2] + (float)p1[2];
  v.w = xv.w + bv.w + (float)p0[3] + (float)p1[3];
  ((float4*)(xmid + (size_t)t * E_DIM))[tid] = v;

  float sm  = v.x + v.y + v.z + v.w;
  float ss = v.x*v.x + v.y*v.y + v.z*v.z + v.w*v.w;
#pragma unroll
  for (int off = 1; off < 64; off <<= 1) {
    sm += __shfl_xor(sm, off);
    ss += __shfl_xor(ss, off);
  }
  __shared__ float rs[4], rss[4];
  const int wave = tid >> 6;
  if ((tid & 63) == 0) { rs[wave] = sm; rss[wave] = ss; }
  __syncthreads();
  sm = rs[0] + rs[1] + rs[2] + rs[3];
  ss = rss[0] + rss[1] + rss[2] + rss[3];
  const float mu   = sm * (1.f / E_DIM);
  const float rstd = rsqrtf(ss * (1.f / E_DIM) - mu * mu + 1e-5f);
  const float4 g4 = ((const float4*)gam)[tid];
  const float4 b4 = ((const float4*)bet)[tid];
  bf16* o = hbuf + (size_t)t * E_DIM + tid * 4;
  o[0] = (bf16)((v.x - mu) * rstd * g4.x + b4.x);
  o[1] = (bf16)((v.y - mu) * rstd * g4.y + b4.y);
  o[2] = (bf16)((v.z - mu) * rstd * g4.z + b4.z);
  o[3] = (bf16)((v.w - mu) * rstd * g4.w + b4.w);
}

// --------------- reduce out bf16 partials (x4) + bias + residual -> out
__global__ __launch_bounds__(256) void reduce_out(
    const float* __restrict__ xmid, const float* __restrict__ bias,
    const bf16* __restrict__ op, float* __restrict__ out)
{
  const int i4 = blockIdx.x * 256 + threadIdx.x;  // 4-el granule, < 2^20
  const int e4 = i4 & 255;
  const size_t base = (size_t)i4 * 4;
  const size_t stride = (size_t)S_SEQ * B_BATCH * E_DIM;
  const float4 a = ((const float4*)xmid)[i4];
  const float4 bv = ((const float4*)bias)[e4];
  const bf16x4 p0 = *(const bf16x4*)&op[base];
  const bf16x4 p1 = *(const bf16x4*)&op[base + stride];
  const bf16x4 p2 = *(const bf16x4*)&op[base + 2 * stride];
  const bf16x4 p3 = *(const bf16x4*)&op[base + 3 * stride];
  float4 o;
  o.x = a.x + bv.x + (float)p0[0] + (float)p1[0] + (float)p2[0] + (float)p3[0];
  o.y = a.y + bv.y + (float)p0[1] + (float)p1[1] + (float)p2[1] + (float)p3[1];
  o.z = a.z + bv.z + (float)p0[2] + (float)p1[2] + (float)p2[2] + (float)p3[2];
  o.w = a.w + bv.w + (float)p0[3] + (float)p1[3] + (float)p2[3] + (float)p3[3];
  ((float4*)out)[i4] = o;
}

// ------------------------------------- fused transpose f32->bf16 (all weights)
__global__ __launch_bounds__(256) void transpose_all(
    const float* __restrict__ w_attn, bf16* __restrict__ wT_attn,
    const float* __restrict__ w_proj, bf16* __restrict__ wT_proj,
    const float* __restrict__ w_fc,   bf16* __restrict__ wT_fc,
    const float* __restrict__ w_out,  bf16* __restrict__ wT_out)
{
  int bid = blockIdx.x;
  const float* in; bf16* outp; int R, C, bx;
  if (bid < 3072)      { in = w_attn; outp = wT_attn; R = 1024; C = 3072; bx = 96; }
  else if (bid < 4096) { in = w_proj; outp = wT_proj; R = 1024; C = 1024; bx = 32; bid -= 3072; }
  else if (bid < 8192) { in = w_fc;   outp = wT_fc;   R = 1024; C = 4096; bx = 128; bid -= 4096; }
  else                 { in = w_out;  outp = wT_out;  R = 4096; C = 1024; bx = 32; bid -= 8192; }
  __shared__ float tile[32][33];
  const int tx = threadIdx.x & 31;
  const int ty = threadIdx.x >> 5;
  const int c0 = (bid % bx) * 32;
  const int r0 = (bid / bx) * 32;
#pragma unroll
  for (int k = 0; k < 4; ++k)
    tile[ty + k*8][tx] = in[(size_t)(r0 + ty + k*8) * C + c0 + tx];
  __syncthreads();
#pragma unroll
  for (int k = 0; k < 4; ++k)
    outp[(size_t)(c0 + ty + k*8) * R + r0 + tx] = (bf16)tile[tx][ty + k*8];
}

// ------------------------------------------------------------------ layernorm
__global__ __launch_bounds__(256) void layernorm_bf16(
    const float* __restrict__ x, const float* __restrict__ gam,
    const float* __restrict__ bet, bf16* __restrict__ out)
{
  const int t = blockIdx.x;
  const int tid = threadIdx.x;
  const float4 v = ((const float4*)(x + (size_t)t * E_DIM))[tid];
  float s  = v.x + v.y + v.z + v.w;
  float ss = v.x*v.x + v.y*v.y + v.z*v.z + v.w*v.w;
#pragma unroll
  for (int off = 1; off < 64; off <<= 1) {
    s  += __shfl_xor(s, off);
    ss += __shfl_xor(ss, off);
  }
  __shared__ float rs[4], rss[4];
  const int wave = tid >> 6;
  if ((tid & 63) == 0) { rs[wave] = s; rss[wave] = ss; }
  __syncthreads();
  s  = rs[0] + rs[1] + rs[2] + rs[3];
  ss = rss[0] + rss[1] + rss[2] + rss[3];
  const float mu   = s * (1.f / E_DIM);
  const float rstd = rsqrtf(ss * (1.f / E_DIM) - mu * mu + 1e-5f);
  const float4 g4 = ((const float4*)gam)[tid];
  const float4 b4 = ((const float4*)bet)[tid];
  bf16* o = out + (size_t)t * E_DIM + tid * 4;
  o[0] = (bf16)((v.x - mu) * rstd * g4.x + b4.x);
  o[1] = (bf16)((v.y - mu) * rstd * g4.y + b4.y);
  o[2] = (bf16)((v.z - mu) * rstd * g4.z + b4.z);
  o[3] = (bf16)((v.w - mu) * rstd * g4.w + b4.w);
}

// ------------------------------- V transpose: vk [head][S][64] -> vt [head][64][S]
__global__ __launch_bounds__(256) void transpose_v(
    const bf16* __restrict__ vk, bf16* __restrict__ vt)
{
  __shared__ bf16 tile[64 * 66];
  const int head = blockIdx.y;
  const int s0 = blockIdx.x * 64;
  const int tid = threadIdx.x;
  for (int f = tid; f < 512; f += 256) {
    const int s = f >> 3, g = f & 7;
    const bf16x8 val = *(const bf16x8*)&vk[((size_t)head * S_SEQ + s0 + s) * 64 + g * 8];
#pragma unroll
    for (int i = 0; i < 8; ++i) tile[s * 66 + g * 8 + i] = val[i];
  }
  __syncthreads();
  for (int f = tid; f < 512; f += 256) {
    const int d = f >> 3, g = f & 7;
    bf16x8 o;
#pragma unroll
    for (int i = 0; i < 8; ++i) o[i] = tile[(g * 8 + i) * 66 + d];
    *(bf16x8*)&vt[((size_t)head * 64 + d) * S_SEQ + s0 + g * 8] = o;
  }
}

// ---------------------------------------------------- flash attention (MFMA)
// Q,K: [head][S][64] bf16 (Q pre-scaled by 1/(8 ln2) -> use exp2);
// Vt: [head][64][S] bf16; Out: [B][S][E] bf16 (merged heads).
// r12 lesson: direct-global frags = per-MFMA 200cy scattered-load chain
// (121us, MfmaUtil 5%). Staging is the coalescing converter — keep it, but
// make it CHEAP: global_load_lds double-buffered (GEMM's proven machinery),
// ONE barrier per KV-tile (r9 ledger: vmcnt(0) gate [stage(t) had a full
// tile to land]; barrier [tile-(t-1) ds_reads consumed by pre-barrier
// MFMAs]; stage(t+1) -> slot (t-1)&1). Staging overlaps previous tile's
// compute; no reg round-trip. K/V tiles 64x64 linear with XOR granule
// swizzle (source (lg^lr)*8, read granule (ks*4+quad)^(row&7): 2-way=free).
// LDS 41KB -> 3 blocks/CU. Softmax: p=2^s direct (scores bounded), Ps pad
// 68 wave-private, l reduced once at the end.
#define AT_PAD 68
__global__ __launch_bounds__(256) void attn_mfma(
    const bf16* __restrict__ Q, const bf16* __restrict__ K,
    const bf16* __restrict__ Vt, bf16* __restrict__ Out)
{
  __shared__ bf16 Ks[2][4096];          //  8 KB x2: K tile 64 rows x 64
  __shared__ bf16 Vs[2][4096];          //  8 KB x2: Vt tile 64 rows(d) x 64
  __shared__ bf16 Ps[64 * AT_PAD];      //  8.7 KB
  const int head = blockIdx.x;
  const int q0 = blockIdx.y * 64;
  const int tid = threadIdx.x;
  const int wave = tid >> 6, lane = tid & 63;
  const int quad = lane >> 4, ln16 = lane & 15;

  // Q A-fragments direct from global (row = q-index, 8 contiguous k-elements)
  const bf16* qg = Q + ((size_t)head * S_SEQ + q0) * 64;
  bf16x8 qfr[2];
#pragma unroll
  for (int ks = 0; ks < 2; ++ks)
    qfr[ks] = *(const bf16x8*)&qg[(size_t)(wave * 16 + ln16) * 64 + ks * 32 + quad * 8];

  f32x4 Oa[4];
  float l_i[4];
#pragma unroll
  for (int j = 0; j < 4; ++j) Oa[j] = (f32x4){0.f, 0.f, 0.f, 0.f};
#pragma unroll
  for (int r = 0; r < 4; ++r) l_i[r] = 0.f;

  const bf16* kg = K + (size_t)head * S_SEQ * 64;
  const bf16* vg = Vt + (size_t)head * 64 * S_SEQ;
  const int qrow = wave * 16;

  // staging: wave covers 8 rows x 8 granules per sweep; 2 sweeps (rows
  // wave*8 and wave*8+32) x {K,V} = 4 gload_lds / thread / tile.
  const int lr = lane >> 3, lg = lane & 7;
  const int gsrc = (lg ^ lr) * 8;       // pre-swizzled source granule
  auto stage = [&](int kt, int ss) {
#pragma unroll
    for (int i = 0; i < 2; ++i) {
      const int row = wave * 8 + i * 32;            // 4 waves x2 = 64 rows
      cp_async16(kg + (size_t)(kt + row + lr) * 64 + gsrc,
                 &Ks[ss][row * 64] + wave * 0);     // wave-uniform base below
    }
#pragma unroll
    for (int i = 0; i < 2; ++i) {
      const int row = wave * 8 + i * 32;
      cp_async16(vg + (size_t)(row + lr) * S_SEQ + kt + gsrc,
                 &Vs[ss][row * 64]);
    }
  };

  stage(0, 0);
  for (int t = 0; t < 16; ++t) {
    const int kt = t * 64;
    asm volatile("s_waitcnt vmcnt(0)" ::: "memory");  // stage(t) landed
    __builtin_amdgcn_s_barrier();       // publish tile t; slot (t+1)&1 free
    if (t + 1 < 16) stage((t + 1) * 64, (t + 1) & 1);

    const bf16* Kt = Ks[t & 1];
    const bf16* Vvt = Vs[t & 1];

    // ---- S = Q K^T (swizzled frag reads, row = kt-local k index)
    f32x4 sacc[4];
#pragma unroll
    for (int jn = 0; jn < 4; ++jn) sacc[jn] = (f32x4){0.f, 0.f, 0.f, 0.f};
#pragma unroll
    for (int ks = 0; ks < 2; ++ks) {
      const int g8 = ((ks * 4 + quad) ^ (ln16 & 7)) * 8;
#pragma unroll
      for (int jn = 0; jn < 4; ++jn) {
        const bf16x8 kf = *(const bf16x8*)&Kt[(jn * 16 + ln16) * 64 + g8];
        sacc[jn] = __builtin_amdgcn_mfma_f32_16x16x32_bf16(qfr[ks], kf, sacc[jn], 0, 0, 0);
      }
    }
    // ---- unnormalized softmax: p = 2^s (C-layout row = quad*4+r)
#pragma unroll
    for (int r = 0; r < 4; ++r) {
      const float p0 = exp2f(sacc[0][r]);
      const float p1 = exp2f(sacc[1][r]);
      const float p2 = exp2f(sacc[2][r]);
      const float p3 = exp2f(sacc[3][r]);
      l_i[r] += (p0 + p1) + (p2 + p3);
      const int prow = qrow + quad * 4 + r;
      Ps[prow * AT_PAD +  0 + ln16] = (bf16)p0;
      Ps[prow * AT_PAD + 16 + ln16] = (bf16)p1;
      Ps[prow * AT_PAD + 32 + ln16] = (bf16)p2;
      Ps[prow * AT_PAD + 48 + ln16] = (bf16)p3;
    }
    // P round-trip is wave-local (rows qrow..qrow+15): LDS drain, no barrier
    asm volatile("s_waitcnt lgkmcnt(0)" ::: "memory");
    // ---- O += P V (Vs row = d, swizzled within-tile k offset)
#pragma unroll
    for (int ks = 0; ks < 2; ++ks) {
      const int g8 = ((ks * 4 + quad) ^ (ln16 & 7)) * 8;
      const bf16x8 pf = *(const bf16x8*)&Ps[(qrow + ln16) * AT_PAD + ks*32 + quad*8];
#pragma unroll
      for (int jn = 0; jn < 4; ++jn) {
        const bf16x8 vf = *(const bf16x8*)&Vvt[(jn * 16 + ln16) * 64 + g8];
        Oa[jn] = __builtin_amdgcn_mfma_f32_16x16x32_bf16(pf, vf, Oa[jn], 0, 0, 0);
      }
    }
  }

  // final l reduction across the 16 lanes of each row group (deferred, once)
#pragma unroll
  for (int r = 0; r < 4; ++r) {
    float l = l_i[r];
#pragma unroll
    for (int off = 1; off < 16; off <<= 1) l += __shfl_xor(l, off);
    l_i[r] = 1.f / l;
  }

  const int b = head >> 4, h = head & 15;
#pragma unroll
  for (int jn = 0; jn < 4; ++jn)
#pragma unroll
    for (int r = 0; r < 4; ++r) {
      const int srow = q0 + qrow + quad * 4 + r;
      Out[((size_t)(b * S_SEQ) + srow) * E_DIM + h * 64 + jn * 16 + ln16] =
          (bf16)(Oa[jn][r] * l_i[r]);
    }
}

// -------------------------------------------------------------------- launch
extern "C" void kernel_launch(void* const* d_in, const int* in_sizes, int n_in,
                              void* d_out, int out_size, void* d_ws, size_t ws_size,
                              hipStream_t stream)
{
  const float* x      = (const float*)d_in[0];
  const float* ln1_g  = (const float*)d_in[1];
  const float* ln1_b  = (const float*)d_in[2];
  const float* w_attn = (const float*)d_in[3];
  const float* b_attn = (const float*)d_in[4];
  const float* w_proj = (const float*)d_in[5];
  const float* b_proj = (const float*)d_in[6];
  const float* ln2_g  = (const float*)d_in[7];
  const float* ln2_b  = (const float*)d_in[8];
  const float* w_fc   = (const float*)d_in[9];
  const float* b_fc   = (const float*)d_in[10];
  const float* w_out  = (const float*)d_in[11];
  const float* b_out  = (const float*)d_in[12];
  float* out = (float*)d_out;

  char* p = (char*)d_ws;
  bf16* wT_attn = (bf16*)p; p += (size_t)3072 * 1024 * 2;   //  6 MB
  bf16* wT_proj = (bf16*)p; p += (size_t)1024 * 1024 * 2;   //  2 MB
  bf16* wT_fc   = (bf16*)p; p += (size_t)4096 * 1024 * 2;   //  8 MB
  bf16* wT_out  = (bf16*)p; p += (size_t)1024 * 4096 * 2;   //  8 MB
  bf16* hbuf    = (bf16*)p; p += (size_t)4096 * 1024 * 2;   //  8 MB (also amerged)
  bf16* amerged = hbuf;       // lifetime [attn, proj_sk] inside hbuf's idle window
  bf16* mfc     = (bf16*)p; p += (size_t)4096 * 4096 * 2;   // 32 MB
  char* part    = p;        p += (size_t)64 * 1024 * 1024;  // 64 MB union
  bf16*  qsplit   = (bf16*)part;                               // q,k,vk: 24 MB
  bf16*  vtb      = (bf16*)(part + (size_t)24 * 1024 * 1024); //  8 MB
  bf16*  projpart = (bf16*)(part + (size_t)32 * 1024 * 1024); // 16 MB (bf16 x2)
  bf16*  outpart  = (bf16*)part;                               // 32 MB (bf16 x4, later)
  float* xmid   = (float*)p; p += (size_t)4194304 * 4;      // 16 MB

  transpose_all<<<12288, 256, 0, stream>>>(w_attn, wT_attn, w_proj, wT_proj,
                                           w_fc, wT_fc, w_out, wT_out);

  layernorm_bf16<<<4096, 256, 0, stream>>>(x, ln1_g, ln1_b, hbuf);
  // qkv GEMM with fused head-split epilogue (mode 3) -> qsplit {q,k,vk}
  gemm256<<<dim3(12, 16), 512, 0, stream>>>(hbuf, wT_attn, b_attn, qsplit,
                                            4096, 3072, 1024, 1024, 3);
  transpose_v<<<dim3(16, 64), 256, 0, stream>>>(qsplit + (size_t)2 * 4194304, vtb);
  attn_mfma<<<dim3(64, 16), 256, 0, stream>>>(qsplit, qsplit + 4194304, vtb, amerged);
  // proj: split-K x2 bf16 partials, fused reduce(+bias+residual)+LN2
  gemm256<<<dim3(4, 16, 2), 512, 0, stream>>>(amerged, wT_proj, nullptr, projpart,
                                              4096, 1024, 1024, 512, 1);
  reduce_proj_ln<<<4096, 256, 0, stream>>>(x, b_proj, projpart, ln2_g, ln2_b,
                                           xmid, hbuf);
  gemm256<<<dim3(16, 16), 512, 0, stream>>>(hbuf, wT_fc, b_fc, mfc,
                                            4096, 4096, 1024, 1024, 2);
  // out: split-K x4 bf16 partials, fused reduce(+bias+residual) -> out
  gemm256<<<dim3(4, 16, 4), 512, 0, stream>>>(mfc, wT_out, nullptr, outpart,
                                              4096, 1024, 4096, 1024, 1);
  reduce_out<<<4096, 256, 0, stream>>>(xmid, b_out, outpart, out);
}

// Round 14
// 329.362 us; speedup vs baseline: 1.2414x; 1.0292x over previous
//
#include <hip/hip_runtime.h>

// build-id: r14-r9base-fast-transpose

#define E_DIM 1024
#define H_DIM 16
#define D_DIM 64
#define S_SEQ 1024
#define B_BATCH 4

typedef __bf16 bf16;
typedef __attribute__((ext_vector_type(8))) __bf16 bf16x8;
typedef __attribute__((ext_vector_type(4))) __bf16 bf16x4;
typedef __attribute__((ext_vector_type(4))) float f32x4;

// ---------------------------------------------------------------- async copy
__device__ __forceinline__ void cp_async16(const bf16* g, bf16* l) {
  __builtin_amdgcn_global_load_lds(
      (const __attribute__((address_space(1))) void*)g,
      (__attribute__((address_space(3))) void*)l, 16, 0, 0);
}

// ---------------------------------------------------------------- GEMM (B^T)
// C[M,N] = A[:,z*Kper..+Kper] * BT[:,z*Kper..+Kper]^T (+ bias)
// modes: 1 = bf16 row-major (z-offset partials), 2 = gelu->bf16, 3 = qkv-split
// r9 kernel verbatim (measured best: fc 49us, MfmaUtil 26%, 92 VGPR).
// BM=BN=256, BK=64, 512 thr = 8 waves (2Mx4N), per-wave 128x64, acc[8][4].
// Schedule-structure experiments r1-r11 (drain-0 / coarse ring / phase-split
// / minimal / 8-phase) all pin at 22-26% MfmaUtil -> schedule is not the
// lever at this size; minimal sync is fastest. Per K-tile:
//   gate vmcnt(0); s_barrier; stage(t+1) -> freed slot; 24 ds_read; 64 MFMA.
// Staging: 8 rows x 128 B sweeps; granule g of row r at slot g^(r&7) via
// pre-swizzled global source (gload_lds linear-dest constraint).
#define BM 256
#define BN 256
#define BK 64
#define BOFF 32768           // elements: B slots start after 2 A slots
#define CS_STRIDE 264        // epilogue C-stage row stride (256 + 8)

__global__ __launch_bounds__(512, 2) void gemm256(
    const bf16* __restrict__ A, const bf16* __restrict__ BT,
    const float* __restrict__ bias, void* __restrict__ Cout,
    int M, int N, int Ktot, int Kper, int mode)
{
  __shared__ bf16 smem[67584];          // 135168 B: ring 65536 el, C-stage 67584
  const int tid  = threadIdx.x;
  const int wave = tid >> 6;
  const int lane = tid & 63;
  const int quad = lane >> 4;
  const int ln16 = lane & 15;
  const int wr = wave >> 2;             // 0..1  (row half of 256)
  const int wc = wave & 3;              // 0..3  (col quarter of 256)
  const int z  = blockIdx.z;

  // bijective XCD-chunk swizzle (all grids have nwg % 8 == 0)
  const int nwg = gridDim.x * gridDim.y;
  int id = blockIdx.y * gridDim.x + blockIdx.x;
  id = (id & 7) * (nwg >> 3) + (id >> 3);
  const int bn = (id % gridDim.x) * BN;
  const int bm = (id / gridDim.x) * BM;

  // staging: per sweep, wave covers 8 rows x 8 granules (128 B rows);
  // lane = lr*8+lg; 4 sweeps x 64 rows cover 256 rows per operand.
  const int lr = lane >> 3;             // row offset within 8-row stripe
  const int lg = lane & 7;              // dest granule slot
  const int gsrc = (lg ^ lr) * 8;       // swizzled source granule (elements)
  const bf16* Ag = A  + (size_t)(bm + wave * 8 + lr) * Ktot + (size_t)z * Kper + gsrc;
  const bf16* Bg = BT + (size_t)(bn + wave * 8 + lr) * Ktot + (size_t)z * Kper + gsrc;

  f32x4 acc[8][4];
#pragma unroll
  for (int i = 0; i < 8; ++i)
#pragma unroll
    for (int j = 0; j < 4; ++j) acc[i][j] = (f32x4){0.f, 0.f, 0.f, 0.f};

  // stage K-tile tt into dbuf slot ss: A 4 sweeps + B 4 sweeps (8 vmem/thread)
  auto stage = [&](int tt, int ss) {
    const size_t ko = (size_t)tt * BK;
    bf16* AsW = smem + ss * 16384 + wave * 512;          // wave-uniform
    bf16* BsW = smem + BOFF + ss * 16384 + wave * 512;
#pragma unroll
    for (int i = 0; i < 4; ++i) {
      cp_async16(Ag + ko + (size_t)(i * 64) * Ktot, AsW + i * 4096);
      cp_async16(Bg + ko + (size_t)(i * 64) * Ktot, BsW + i * 4096);
    }
  };

  const int nt = Kper >> 6;             // BK=64; >= 8 for all call sites
  stage(0, 0);

  for (int t = 0; t < nt; ++t) {
    // gate: only outstanding vmem = stage(t), issued one iteration ago
    asm volatile("s_waitcnt vmcnt(0)" ::: "memory");
    __builtin_amdgcn_s_barrier();       // publish tile t; slot (t+1)&1 free

    if (t + 1 < nt) stage(t + 1, (t + 1) & 1);

    const bf16* At = smem + (t & 1) * 16384;
    const bf16* Bt = smem + BOFF + (t & 1) * 16384;
#pragma unroll
    for (int ks = 0; ks < 2; ++ks) {
      const int g8 = ((ks * 4 + quad) ^ (ln16 & 7)) * 8;
      bf16x8 afr[8], bfr[4];
#pragma unroll
      for (int j = 0; j < 4; ++j)
        bfr[j] = *(const bf16x8*)&Bt[(wc * 64 + j * 16 + ln16) * 64 + g8];
#pragma unroll
      for (int i = 0; i < 8; ++i)
        afr[i] = *(const bf16x8*)&At[(wr * 128 + i * 16 + ln16) * 64 + g8];
#pragma unroll
      for (int i = 0; i < 8; ++i)
#pragma unroll
        for (int j = 0; j < 4; ++j)
          acc[i][j] = __builtin_amdgcn_mfma_f32_16x16x32_bf16(
              afr[i], bfr[j], acc[i][j], 0, 0, 0);
    }
  }

  // ---- epilogue: single-pass LDS stage, coalesced 16B stores
  __syncthreads();
  const int which = bn >> 10;           // mode 3: 0=q 1=k 2=v
  const int h0    = (bn & 1023) >> 6;   // first of 4 heads in this tile
  bf16* Cb = (bf16*)Cout;

#pragma unroll
  for (int j = 0; j < 4; ++j) {
    const int col = wc * 64 + j * 16 + ln16;
    const float bv = bias ? bias[bn + col] : 0.f;
#pragma unroll
    for (int i = 0; i < 8; ++i) {
      const int row0 = wr * 128 + i * 16 + quad * 4;
#pragma unroll
      for (int r = 0; r < 4; ++r) {
        float v = acc[i][j][r] + bv;
        if (mode == 2)
          v = v / (1.f + __expf(-1.5957691216057308f * (v + 0.044715f * v * v * v)));
        else if (mode == 3 && which == 0)
          v *= 0.18033688011112042f;    // 0.125 / ln2 (attn uses exp2)
        smem[(row0 + r) * CS_STRIDE + col] = (bf16)v;
      }
    }
  }
  __syncthreads();
  if (mode == 3) {
#pragma unroll
    for (int pass = 0; pass < 16; ++pass) {
      const int f = pass * 512 + tid;          // 8192 granules (256 x 32)
      const int row = f >> 5, cg = f & 31;
      const bf16x8 val = *(const bf16x8*)&smem[row * CS_STRIDE + cg * 8];
      const int sb = bm + row;
      const int s = sb >> 2, b = sb & 3;
      const int h = h0 + (cg >> 3), d8 = cg & 7;
      bf16* dst = Cb + (size_t)which * 4194304
                + ((size_t)(b * 16 + h) * 1024 + s) * 64 + d8 * 8;
      *(bf16x8*)dst = val;
    }
  } else {
    bf16* Cz = Cb + (size_t)z * M * N;
#pragma unroll
    for (int pass = 0; pass < 16; ++pass) {
      const int f = pass * 512 + tid;
      const int row = f >> 5, cg = f & 31;
      const bf16x8 val = *(const bf16x8*)&smem[row * CS_STRIDE + cg * 8];
      *(bf16x8*)(Cz + (size_t)(bm + row) * N + bn + cg * 8) = val;
    }
  }
}

// ------ fused: reduce proj bf16 partials + bias + residual -> xmid, + LN2 -> hbuf
// pp rows are (b*S+s); x/xmid rows are (s*B+b)
__global__ __launch_bounds__(256) void reduce_proj_ln(
    const float* __restrict__ x, const float* __restrict__ bias,
    const bf16* __restrict__ pp, const float* __restrict__ gam,
    const float* __restrict__ bet, float* __restrict__ xmid,
    bf16* __restrict__ hbuf)
{
  const int t = blockIdx.x;               // row in (s*B+b) order
  const int tid = threadIdx.x;
  const int s = t >> 2, b = t & 3;
  const size_t prow = ((size_t)(b * S_SEQ + s)) * E_DIM + tid * 4;
  const float4 xv = ((const float4*)(x + (size_t)t * E_DIM))[tid];
  const float4 bv = ((const float4*)bias)[tid];
  const bf16x4 p0 = *(const bf16x4*)&pp[prow];
  const bf16x4 p1 = *(const bf16x4*)&pp[prow + (size_t)S_SEQ * B_BATCH * E_DIM];
  float4 v;
  v.x = xv.x + bv.x + (float)p0[0] + (float)p1[0];
  v.y = xv.y + bv.y + (float)p0[1] + (float)p1[1];
  v.z = xv.z + bv.z + (float)p0[2] + (float)p1[2];
  v.w = xv.w + bv.w + (float)p0[3] + (float)p1[3];
  ((float4*)(xmid + (size_t)t * E_DIM))[tid] = v;

  float sm  = v.x + v.y + v.z + v.w;
  float ss = v.x*v.x + v.y*v.y + v.z*v.z + v.w*v.w;
#pragma unroll
  for (int off = 1; off < 64; off <<= 1) {
    sm += __shfl_xor(sm, off);
    ss += __shfl_xor(ss, off);
  }
  __shared__ float rs[4], rss[4];
  const int wave = tid >> 6;
  if ((tid & 63) == 0) { rs[wave] = sm; rss[wave] = ss; }
  __syncthreads();
  sm = rs[0] + rs[1] + rs[2] + rs[3];
  ss = rss[0] + rss[1] + rss[2] + rss[3];
  const float mu   = sm * (1.f / E_DIM);
  const float rstd = rsqrtf(ss * (1.f / E_DIM) - mu * mu + 1e-5f);
  const float4 g4 = ((const float4*)gam)[tid];
  const float4 b4 = ((const float4*)bet)[tid];
  bf16* o = hbuf + (size_t)t * E_DIM + tid * 4;
  o[0] = (bf16)((v.x - mu) * rstd * g4.x + b4.x);
  o[1] = (bf16)((v.y - mu) * rstd * g4.y + b4.y);
  o[2] = (bf16)((v.z - mu) * rstd * g4.z + b4.z);
  o[3] = (bf16)((v.w - mu) * rstd * g4.w + b4.w);
}

// --------------- reduce out bf16 partials (x4) + bias + residual -> out
__global__ __launch_bounds__(256) void reduce_out(
    const float* __restrict__ xmid, const float* __restrict__ bias,
    const bf16* __restrict__ op, float* __restrict__ out)
{
  const int i4 = blockIdx.x * 256 + threadIdx.x;  // 4-el granule, < 2^20
  const int e4 = i4 & 255;
  const size_t base = (size_t)i4 * 4;
  const size_t stride = (size_t)S_SEQ * B_BATCH * E_DIM;
  const float4 a = ((const float4*)xmid)[i4];
  const float4 bv = ((const float4*)bias)[e4];
  const bf16x4 p0 = *(const bf16x4*)&op[base];
  const bf16x4 p1 = *(const bf16x4*)&op[base + stride];
  const bf16x4 p2 = *(const bf16x4*)&op[base + 2 * stride];
  const bf16x4 p3 = *(const bf16x4*)&op[base + 3 * stride];
  float4 o;
  o.x = a.x + bv.x + (float)p0[0] + (float)p1[0] + (float)p2[0] + (float)p3[0];
  o.y = a.y + bv.y + (float)p0[1] + (float)p1[1] + (float)p2[1] + (float)p3[1];
  o.z = a.z + bv.z + (float)p0[2] + (float)p1[2] + (float)p2[2] + (float)p3[2];
  o.w = a.w + bv.w + (float)p0[3] + (float)p1[3] + (float)p2[3] + (float)p3[3];
  ((float4*)out)[i4] = o;
}

// ------------- fused transpose f32->bf16 (all weights), 64x64 vectorized
// 3072 blocks (was 12288): float4 coalesced loads, LDS f32 [64][65]
// (write conflict-free; read banks 8*(l&3)+(l>>3): 2-way = free),
// bf16x8 16B stores (8-lane groups cover 128B contiguous output).
__global__ __launch_bounds__(256) void transpose_all(
    const float* __restrict__ w_attn, bf16* __restrict__ wT_attn,
    const float* __restrict__ w_proj, bf16* __restrict__ wT_proj,
    const float* __restrict__ w_fc,   bf16* __restrict__ wT_fc,
    const float* __restrict__ w_out,  bf16* __restrict__ wT_out)
{
  int bid = blockIdx.x;
  const float* in; bf16* outp; int R, C, bx;
  if (bid < 768)       { in = w_attn; outp = wT_attn; R = 1024; C = 3072; bx = 48; }
  else if (bid < 1024) { in = w_proj; outp = wT_proj; R = 1024; C = 1024; bx = 16; bid -= 768; }
  else if (bid < 2048) { in = w_fc;   outp = wT_fc;   R = 1024; C = 4096; bx = 64; bid -= 1024; }
  else                 { in = w_out;  outp = wT_out;  R = 4096; C = 1024; bx = 16; bid -= 2048; }
  __shared__ float tile[64][65];        // 16.6 KB
  const int c0 = (bid % bx) * 64;
  const int r0 = (bid / bx) * 64;
  const int tr = threadIdx.x >> 4;          // 0..15
  const int tc = (threadIdx.x & 15) * 4;    // 0..60
#pragma unroll
  for (int k = 0; k < 4; ++k) {
    const float4 v = *(const float4*)&in[(size_t)(r0 + tr + k * 16) * C + c0 + tc];
    tile[tr + k * 16][tc]     = v.x;
    tile[tr + k * 16][tc + 1] = v.y;
    tile[tr + k * 16][tc + 2] = v.z;
    tile[tr + k * 16][tc + 3] = v.w;
  }
  __syncthreads();
#pragma unroll
  for (int p = 0; p < 2; ++p) {
    const int g = p * 256 + threadIdx.x;      // 512 granules (64 c x 8 r8)
    const int cl = g >> 3, r8 = (g & 7) * 8;
    bf16x8 o;
#pragma unroll
    for (int k = 0; k < 8; ++k) o[k] = (bf16)tile[r8 + k][cl];
    *(bf16x8*)&outp[(size_t)(c0 + cl) * R + r0 + r8] = o;
  }
}

// ------------------------------------------------------------------ layernorm
__global__ __launch_bounds__(256) void layernorm_bf16(
    const float* __restrict__ x, const float* __restrict__ gam,
    const float* __restrict__ bet, bf16* __restrict__ out)
{
  const int t = blockIdx.x;
  const int tid = threadIdx.x;
  const float4 v = ((const float4*)(x + (size_t)t * E_DIM))[tid];
  float s  = v.x + v.y + v.z + v.w;
  float ss = v.x*v.x + v.y*v.y + v.z*v.z + v.w*v.w;
#pragma unroll
  for (int off = 1; off < 64; off <<= 1) {
    s  += __shfl_xor(s, off);
    ss += __shfl_xor(ss, off);
  }
  __shared__ float rs[4], rss[4];
  const int wave = tid >> 6;
  if ((tid & 63) == 0) { rs[wave] = s; rss[wave] = ss; }
  __syncthreads();
  s  = rs[0] + rs[1] + rs[2] + rs[3];
  ss = rss[0] + rss[1] + rss[2] + rss[3];
  const float mu   = s * (1.f / E_DIM);
  const float rstd = rsqrtf(ss * (1.f / E_DIM) - mu * mu + 1e-5f);
  const float4 g4 = ((const float4*)gam)[tid];
  const float4 b4 = ((const float4*)bet)[tid];
  bf16* o = out + (size_t)t * E_DIM + tid * 4;
  o[0] = (bf16)((v.x - mu) * rstd * g4.x + b4.x);
  o[1] = (bf16)((v.y - mu) * rstd * g4.y + b4.y);
  o[2] = (bf16)((v.z - mu) * rstd * g4.z + b4.z);
  o[3] = (bf16)((v.w - mu) * rstd * g4.w + b4.w);
}

// ------------------------------- V transpose: vk [head][S][64] -> vt [head][64][S]
__global__ __launch_bounds__(256) void transpose_v(
    const bf16* __restrict__ vk, bf16* __restrict__ vt)
{
  __shared__ bf16 tile[64 * 66];
  const int head = blockIdx.y;
  const int s0 = blockIdx.x * 64;
  const int tid = threadIdx.x;
  for (int f = tid; f < 512; f += 256) {
    const int s = f >> 3, g = f & 7;
    const bf16x8 val = *(const bf16x8*)&vk[((size_t)head * S_SEQ + s0 + s) * 64 + g * 8];
#pragma unroll
    for (int i = 0; i < 8; ++i) tile[s * 66 + g * 8 + i] = val[i];
  }
  __syncthreads();
  for (int f = tid; f < 512; f += 256) {
    const int d = f >> 3, g = f & 7;
    bf16x8 o;
#pragma unroll
    for (int i = 0; i < 8; ++i) o[i] = tile[(g * 8 + i) * 66 + d];
    *(bf16x8*)&vt[((size_t)head * 64 + d) * S_SEQ + s0 + g * 8] = o;
  }
}

// ---------------------------------------------------- flash attention (MFMA)
// Q,K: [head][S][64] bf16 (Q pre-scaled by 1/(8 ln2) -> use exp2);
// Vt: [head][64][S] bf16; Out: [B][S][E] bf16 (merged heads).
// r4-r11 version (best measured config). 64 q-rows per block (16 per wave).
// NO max-stabilization: scores bounded (|s|<~4), softmax = exp2 direct;
// l reduced across lanes ONCE at the end. AT_PAD=68: conflict-free.
#define AT_PAD 68
__global__ __launch_bounds__(256) void attn_mfma(
    const bf16* __restrict__ Q, const bf16* __restrict__ K,
    const bf16* __restrict__ Vt, bf16* __restrict__ Out)
{
  __shared__ bf16 Ks[64 * AT_PAD];
  __shared__ bf16 Vs[64 * AT_PAD];
  __shared__ bf16 Ps[64 * AT_PAD];
  const int head = blockIdx.x;
  const int q0 = blockIdx.y * 64;
  const int tid = threadIdx.x;
  const int wave = tid >> 6, lane = tid & 63;
  const int quad = lane >> 4, ln16 = lane & 15;

  // Q A-fragments direct from global (row = q-index, 8 contiguous k-elements)
  const bf16* qg = Q + ((size_t)head * S_SEQ + q0) * 64;
  bf16x8 qfr[2];
#pragma unroll
  for (int ks = 0; ks < 2; ++ks)
    qfr[ks] = *(const bf16x8*)&qg[(size_t)(wave * 16 + ln16) * 64 + ks * 32 + quad * 8];

  f32x4 Oa[4];
  float l_i[4];
#pragma unroll
  for (int j = 0; j < 4; ++j) Oa[j] = (f32x4){0.f, 0.f, 0.f, 0.f};
#pragma unroll
  for (int r = 0; r < 4; ++r) l_i[r] = 0.f;

  const bf16* kg = K + (size_t)head * S_SEQ * 64;
  const bf16* vg = Vt + (size_t)head * 64 * S_SEQ;
  const int qrow = wave * 16;

  for (int kt = 0; kt < S_SEQ; kt += 64) {
    __syncthreads();                      // protect Ks/Vs from prior PV reads
    for (int f = tid; f < 512; f += 256) {
      const int r = f >> 3, g = f & 7;
      *(bf16x8*)&Ks[r * AT_PAD + g * 8] = *(const bf16x8*)&kg[(size_t)(kt + r) * 64 + g * 8];
      *(bf16x8*)&Vs[r * AT_PAD + g * 8] = *(const bf16x8*)&vg[(size_t)r * S_SEQ + kt + g * 8];
    }
    __syncthreads();

    // ---- S = Q K^T
    f32x4 sacc[4];
#pragma unroll
    for (int jn = 0; jn < 4; ++jn) sacc[jn] = (f32x4){0.f, 0.f, 0.f, 0.f};
#pragma unroll
    for (int ks = 0; ks < 2; ++ks) {
#pragma unroll
      for (int jn = 0; jn < 4; ++jn) {
        const bf16x8 bf_ = *(const bf16x8*)&Ks[(jn*16 + ln16) * AT_PAD + ks*32 + quad*8];
        sacc[jn] = __builtin_amdgcn_mfma_f32_16x16x32_bf16(qfr[ks], bf_, sacc[jn], 0, 0, 0);
      }
    }
    // ---- unnormalized softmax: p = 2^s (C-layout row = quad*4+r)
#pragma unroll
    for (int r = 0; r < 4; ++r) {
      const float p0 = exp2f(sacc[0][r]);
      const float p1 = exp2f(sacc[1][r]);
      const float p2 = exp2f(sacc[2][r]);
      const float p3 = exp2f(sacc[3][r]);
      l_i[r] += (p0 + p1) + (p2 + p3);
      const int prow = qrow + quad * 4 + r;
      Ps[prow * AT_PAD +  0 + ln16] = (bf16)p0;
      Ps[prow * AT_PAD + 16 + ln16] = (bf16)p1;
      Ps[prow * AT_PAD + 32 + ln16] = (bf16)p2;
      Ps[prow * AT_PAD + 48 + ln16] = (bf16)p3;
    }
    // P round-trip is wave-local (rows qrow..qrow+15): LDS drain, no barrier
    asm volatile("s_waitcnt lgkmcnt(0)" ::: "memory");
    // ---- O += P V
#pragma unroll
    for (int ks = 0; ks < 2; ++ks) {
      const bf16x8 pf = *(const bf16x8*)&Ps[(qrow + ln16) * AT_PAD + ks*32 + quad*8];
#pragma unroll
      for (int jn = 0; jn < 4; ++jn) {
        const bf16x8 vf = *(const bf16x8*)&Vs[(jn*16 + ln16) * AT_PAD + ks*32 + quad*8];
        Oa[jn] = __builtin_amdgcn_mfma_f32_16x16x32_bf16(pf, vf, Oa[jn], 0, 0, 0);
      }
    }
  }

  // final l reduction across the 16 lanes of each row group (deferred, once)
#pragma unroll
  for (int r = 0; r < 4; ++r) {
    float l = l_i[r];
#pragma unroll
    for (int off = 1; off < 16; off <<= 1) l += __shfl_xor(l, off);
    l_i[r] = 1.f / l;
  }

  const int b = head >> 4, h = head & 15;
#pragma unroll
  for (int jn = 0; jn < 4; ++jn)
#pragma unroll
    for (int r = 0; r < 4; ++r) {
      const int srow = q0 + qrow + quad * 4 + r;
      Out[((size_t)(b * S_SEQ) + srow) * E_DIM + h * 64 + jn * 16 + ln16] =
          (bf16)(Oa[jn][r] * l_i[r]);
    }
}

// -------------------------------------------------------------------- launch
extern "C" void kernel_launch(void* const* d_in, const int* in_sizes, int n_in,
                              void* d_out, int out_size, void* d_ws, size_t ws_size,
                              hipStream_t stream)
{
  const float* x      = (const float*)d_in[0];
  const float* ln1_g  = (const float*)d_in[1];
  const float* ln1_b  = (const float*)d_in[2];
  const float* w_attn = (const float*)d_in[3];
  const float* b_attn = (const float*)d_in[4];
  const float* w_proj = (const float*)d_in[5];
  const float* b_proj = (const float*)d_in[6];
  const float* ln2_g  = (const float*)d_in[7];
  const float* ln2_b  = (const float*)d_in[8];
  const float* w_fc   = (const float*)d_in[9];
  const float* b_fc   = (const float*)d_in[10];
  const float* w_out  = (const float*)d_in[11];
  const float* b_out  = (const float*)d_in[12];
  float* out = (float*)d_out;

  char* p = (char*)d_ws;
  bf16* wT_attn = (bf16*)p; p += (size_t)3072 * 1024 * 2;   //  6 MB
  bf16* wT_proj = (bf16*)p; p += (size_t)1024 * 1024 * 2;   //  2 MB
  bf16* wT_fc   = (bf16*)p; p += (size_t)4096 * 1024 * 2;   //  8 MB
  bf16* wT_out  = (bf16*)p; p += (size_t)1024 * 4096 * 2;   //  8 MB
  bf16* hbuf    = (bf16*)p; p += (size_t)4096 * 1024 * 2;   //  8 MB (also amerged)
  bf16* amerged = hbuf;       // lifetime [attn, proj_sk] inside hbuf's idle window
  bf16* mfc     = (bf16*)p; p += (size_t)4096 * 4096 * 2;   // 32 MB
  char* part    = p;        p += (size_t)64 * 1024 * 1024;  // 64 MB union
  bf16*  qsplit   = (bf16*)part;                               // q,k,vk: 24 MB
  bf16*  vtb      = (bf16*)(part + (size_t)24 * 1024 * 1024); //  8 MB
  bf16*  projpart = (bf16*)(part + (size_t)32 * 1024 * 1024); // 16 MB (bf16 x2)
  bf16*  outpart  = (bf16*)part;                               // 32 MB (bf16 x4, later)
  float* xmid   = (float*)p; p += (size_t)4194304 * 4;      // 16 MB

  transpose_all<<<3072, 256, 0, stream>>>(w_attn, wT_attn, w_proj, wT_proj,
                                          w_fc, wT_fc, w_out, wT_out);

  layernorm_bf16<<<4096, 256, 0, stream>>>(x, ln1_g, ln1_b, hbuf);
  // qkv GEMM with fused head-split epilogue (mode 3) -> qsplit {q,k,vk}
  gemm256<<<dim3(12, 16), 512, 0, stream>>>(hbuf, wT_attn, b_attn, qsplit,
                                            4096, 3072, 1024, 1024, 3);
  transpose_v<<<dim3(16, 64), 256, 0, stream>>>(qsplit + (size_t)2 * 4194304, vtb);
  attn_mfma<<<dim3(64, 16), 256, 0, stream>>>(qsplit, qsplit + 4194304, vtb, amerged);
  // proj: split-K x2 bf16 partials, fused reduce(+bias+residual)+LN2
  gemm256<<<dim3(4, 16, 2), 512, 0, stream>>>(amerged, wT_proj, nullptr, projpart,
                                              4096, 1024, 1024, 512, 1);
  reduce_proj_ln<<<4096, 256, 0, stream>>>(x, b_proj, projpart, ln2_g, ln2_b,
                                           xmid, hbuf);
  gemm256<<<dim3(16, 16), 512, 0, stream>>>(hbuf, wT_fc, b_fc, mfc,
                                            4096, 4096, 1024, 1024, 2);
  // out: split-K x4 bf16 partials, fused reduce(+bias+residual) -> out
  gemm256<<<dim3(4, 16, 4), 512, 0, stream>>>(mfc, wT_out, nullptr, outpart,
                                              4096, 1024, 4096, 1024, 1);
  reduce_out<<<4096, 256, 0, stream>>>(xmid, b_out, outpart, out);
}